// Round 15
// baseline (623.206 us; speedup 1.0000x reference)
//
#include <hip/hip_runtime.h>

#define NN 50000
#define NPAD 50048     // 391 * 128
#define NBLK 391
#define NE 400000
#define NBATCH 8
#define NDIM 32
#define EDIM 16
#define H 128
#define NLAYERS 3
#define CHUNK_ELEMS 4096   // node-kernel weight chunk: 2 hilo * 4 nt * 64 lane * 8
#define NODE_CHUNKS 24     // 16 (Wu, K=256) + 8 (uW2, K=128)
#define ZW_CHUNK 8192      // zdzs chunk: 2 hilo * 8 nt * 64 lane * 8
#define NSB 196            // scan blocks: ceil(50000/256)
#define ZEB 128            // edges per block in ze_kernel (4 waves x 32)

typedef __attribute__((ext_vector_type(8))) __bf16 bf16x8;
typedef __attribute__((ext_vector_type(16))) float f32x16;
typedef __attribute__((ext_vector_type(8))) short short8;
typedef __attribute__((ext_vector_type(2))) float v2f;

__device__ __forceinline__ void block_sync_lds() {
  asm volatile("s_waitcnt lgkmcnt(0)\ns_barrier" ::: "memory");
}
__device__ __forceinline__ void wait_lds() {
  asm volatile("s_waitcnt lgkmcnt(0)" ::: "memory");
}
// one dword = 2 packed bf16 -> 2 fp32 (pure bit ops)
__device__ __forceinline__ v2f bf2f(unsigned u) {
  v2f r;
  r.x = __uint_as_float(u << 16);
  r.y = __uint_as_float(u & 0xffff0000u);
  return r;
}

// ---------------- node embedding: h = x @ Wn + bn (bf16 out) ----------------
__global__ __launch_bounds__(128) void embed_nodes_kernel(
    const float* __restrict__ x, const float* __restrict__ Wn,
    const float* __restrict__ bn, __bf16* __restrict__ hb) {
  __shared__ float Ws[NDIM * H];
  __shared__ float xs[16 * NDIM];
  int j = threadIdx.x;
  int nbase = blockIdx.x * 16;
  for (int r = 0; r < NDIM; ++r) Ws[r * H + j] = Wn[r * H + j];
#pragma unroll
  for (int t = 0; t < 4; ++t) {
    int f = j + t * 128;
    xs[f] = x[nbase * NDIM + f];
  }
  __syncthreads();
  float b = bn[j];
  for (int nn = 0; nn < 16; ++nn) {
    float acc = b;
#pragma unroll
    for (int k = 0; k < NDIM; ++k)
      acc = fmaf(xs[nn * NDIM + k], Ws[k * H + j], acc);
    hb[(size_t)(nbase + nn) * H + j] = (__bf16)acc;
  }
}

// ---------------- degree histogram over dst ----------------
__global__ __launch_bounds__(256) void degree_kernel(const int* __restrict__ ei,
                                                     int* __restrict__ deg) {
  int e = blockIdx.x * 256 + threadIdx.x;
  if (e < NE) atomicAdd(&deg[ei[NE + e]], 1);
}

// ---------------- parallel 3-phase exclusive scan of deg -> cursor ----------------
__global__ __launch_bounds__(256) void scan1_kernel(const int* __restrict__ deg,
                                                    int* __restrict__ bsum) {
  __shared__ int ws[4];
  int i = blockIdx.x * 256 + threadIdx.x;
  int lane = threadIdx.x & 63, wid = threadIdx.x >> 6;
  int v = (i < NN) ? deg[i] : 0;
#pragma unroll
  for (int off = 32; off; off >>= 1) v += __shfl_down(v, off);
  if (lane == 0) ws[wid] = v;
  __syncthreads();
  if (threadIdx.x == 0) bsum[blockIdx.x] = ws[0] + ws[1] + ws[2] + ws[3];
}

__global__ __launch_bounds__(256) void scan2_kernel(const int* __restrict__ bsum,
                                                    int* __restrict__ boff) {
  __shared__ int s[256];
  int t = threadIdx.x;
  int v = (t < NSB) ? bsum[t] : 0;
  s[t] = v;
  __syncthreads();
  for (int off = 1; off < 256; off <<= 1) {
    int u = (t >= off) ? s[t - off] : 0;
    __syncthreads();
    s[t] += u;
    __syncthreads();
  }
  if (t < NSB) boff[t] = s[t] - v;  // exclusive across blocks
}

__global__ __launch_bounds__(256) void scan3_kernel(const int* __restrict__ deg,
                                                    const int* __restrict__ boff,
                                                    int* __restrict__ cursor) {
  __shared__ int wsum[4], woff[4];
  int i = blockIdx.x * 256 + threadIdx.x;
  int lane = threadIdx.x & 63, wid = threadIdx.x >> 6;
  int orig = (i < NN) ? deg[i] : 0;
  int v = orig;
#pragma unroll
  for (int off = 1; off < 64; off <<= 1) {
    int u = __shfl_up(v, off);
    if (lane >= off) v += u;
  }
  if (lane == 63) wsum[wid] = v;
  __syncthreads();
  if (threadIdx.x == 0) {
    int r = 0;
#pragma unroll
    for (int w = 0; w < 4; ++w) {
      woff[w] = r;
      r += wsum[w];
    }
  }
  __syncthreads();
  if (i < NN) cursor[i] = (v - orig) + woff[wid] + boff[blockIdx.x];
}

// ---------------- counting-sort scatter: edges grouped by dst ----------------
// after this kernel, cursor[n] == END offset of node n's segment (CSR rowptr).
__global__ __launch_bounds__(256) void scatter_kernel(
    const int* __restrict__ ei, int* __restrict__ cursor,
    int* __restrict__ srcSrt, int* __restrict__ eidSrt) {
  int e = blockIdx.x * 256 + threadIdx.x;
  if (e < NE) {
    int d = ei[NE + e];
    int pos = atomicAdd(&cursor[d], 1);
    srcSrt[pos] = ei[e];
    eidSrt[pos] = e;
  }
}

// ---------------- gather edge attrs into sorted order, fp32 -> bf16 (once) ----------------
__global__ __launch_bounds__(256) void gather_ea_kernel(
    const float* __restrict__ ea, const int* __restrict__ eidSrt,
    __bf16* __restrict__ eaSrt) {
  int fl = blockIdx.x * 256 + threadIdx.x;
  if (fl < NE) {
    int e = eidSrt[fl];
    const float4* ep = (const float4*)(ea + (size_t)e * EDIM);
    __bf16* op = eaSrt + (size_t)fl * EDIM;
#pragma unroll
    for (int q = 0; q < 4; ++q) {
      float4 v = ep[q];
      op[q * 4 + 0] = (__bf16)v.x;
      op[q * 4 + 1] = (__bf16)v.y;
      op[q * 4 + 2] = (__bf16)v.z;
      op[q * 4 + 3] = (__bf16)v.w;
    }
  }
}

// ---------------- zdzs weights: mW1[0:256] -> hi/lo bf16, frag-swizzled ----------------
__global__ __launch_bounds__(256) void precomp_zw_kernel(
    const float* __restrict__ mW1, __bf16* __restrict__ ZW) {
  int l = blockIdx.x / 8;
  int c = blockIdx.x % 8;
  int tid = threadIdx.x;
  const float* w1 = mW1 + (size_t)l * 384 * H;
  __bf16* dst = ZW + ((size_t)l * 8 + c) * ZW_CHUNK;
  for (int it = 0; it < 32; ++it) {
    int flat = it * 256 + tid;
    int j = flat & 7;
    int lane = (flat >> 3) & 63;
    int nt = (flat >> 9) & 7;
    int hilo = flat >> 12;
    int k = c * 16 + ((lane >> 5) << 3) + j;
    int n = nt * 32 + (lane & 31);
    float w = (n < 128) ? w1[(size_t)k * H + n]
                        : w1[(size_t)(128 + k) * H + (n - 128)];
    __bf16 hi = (__bf16)w;
    __bf16 lo = (__bf16)(w - (float)hi);
    dst[flat] = hilo ? lo : hi;
  }
}

// ---------------- Wef = We @ mW1[256:384] (16x128), bm = mb1 + be @ ... ----------------
__global__ __launch_bounds__(128) void precomp_wef_kernel(
    const float* __restrict__ mW1, const float* __restrict__ mb1,
    const float* __restrict__ We, const float* __restrict__ be,
    float* __restrict__ Wef, float* __restrict__ bm) {
  int l = blockIdx.x;
  int n = threadIdx.x;
  const float* w1 = mW1 + (size_t)l * 384 * H;
  float acc[EDIM];
#pragma unroll
  for (int i = 0; i < EDIM; ++i) acc[i] = 0.f;
  float accb = 0.f;
  for (int c = 0; c < H; ++c) {
    float wv = w1[(size_t)(256 + c) * H + n];
    accb = fmaf(be[c], wv, accb);
#pragma unroll
    for (int i = 0; i < EDIM; ++i)
      acc[i] = fmaf(We[i * H + c], wv, acc[i]);
  }
#pragma unroll
  for (int i = 0; i < EDIM; ++i)
    Wef[((size_t)l * EDIM + i) * H + n] = acc[i];
  bm[l * H + n] = mb1[l * H + n] + accb;
}

// ---------------- swizzle Wef into MFMA frag order (hi/lo), K=16 ----------------
__global__ __launch_bounds__(256) void precomp_wefs_kernel(
    const float* __restrict__ Wef, __bf16* __restrict__ WefS) {
  int l = blockIdx.x;
  int tid = threadIdx.x;
  int nt = tid >> 6, lane = tid & 63;
  int n = nt * 32 + (lane & 31);
  int half = lane >> 5;
  const float* wl = Wef + (size_t)l * EDIM * H;
  __bf16* dst = WefS + (size_t)l * CHUNK_ELEMS;
#pragma unroll
  for (int j = 0; j < 8; ++j) {
    int k = half * 8 + j;
    float w = wl[(size_t)k * H + n];
    __bf16 hi = (__bf16)w;
    __bf16 lo = (__bf16)(w - (float)hi);
    dst[((0 * 4 + nt) * 64 + lane) * 8 + j] = hi;
    dst[((1 * 4 + nt) * 64 + lane) * 8 + j] = lo;
  }
}

// ---------------- precompute folded update weights (fp32 Wu) ----------------
__global__ __launch_bounds__(128) void precomp_wu_kernel(
    const float* __restrict__ uW1, const float* __restrict__ mW2,
    const float* __restrict__ mb2, float* __restrict__ Wu,
    float* __restrict__ va) {
  int l = blockIdx.x / 257;
  int r = blockIdx.x % 257;
  int j = threadIdx.x;
  const float* u1 = uW1 + (size_t)l * 256 * H;
  if (r < 128) {
    Wu[((size_t)l * 256 + r) * H + j] = u1[(size_t)r * H + j];
  } else if (r < 256) {
    int i = r - 128;
    const float* m2 = mW2 + ((size_t)l * H + i) * H;
    float s = 0.f;
    for (int c = 0; c < H; ++c)
      s = fmaf(m2[c], u1[(size_t)(128 + c) * H + j], s);
    Wu[((size_t)l * 256 + r) * H + j] = s;
  } else {
    float s = 0.f;
    for (int c = 0; c < H; ++c)
      s = fmaf(mb2[l * H + c], u1[(size_t)(128 + c) * H + j], s);
    va[l * H + j] = s;
  }
}

// ---------------- swizzle node weights into hi/lo frag chunks ----------------
__global__ __launch_bounds__(256) void precomp_wns_kernel(
    const float* __restrict__ Wu, const float* __restrict__ uW2,
    __bf16* __restrict__ WnS) {
  int l = blockIdx.x / NODE_CHUNKS;
  int c = blockIdx.x % NODE_CHUNKS;
  int tid = threadIdx.x;
  int nt = tid >> 6, lane = tid & 63;
  int n = nt * 32 + (lane & 31);
  int half = lane >> 5;
  __bf16* dst = WnS + ((size_t)l * NODE_CHUNKS + c) * CHUNK_ELEMS;
#pragma unroll
  for (int j = 0; j < 8; ++j) {
    float w;
    if (c < 16) {
      int k = c * 16 + half * 8 + j;
      w = Wu[((size_t)l * 256 + k) * H + n];
    } else {
      int k = (c - 16) * 16 + half * 8 + j;
      w = uW2[((size_t)l * H + k) * H + n];
    }
    __bf16 hi = (__bf16)w;
    __bf16 lo = (__bf16)(w - (float)hi);
    dst[((0 * 4 + nt) * 64 + lane) * 8 + j] = hi;
    dst[((1 * 4 + nt) * 64 + lane) * 8 + j] = lo;
  }
}

// ---------------- z = h @ [W_d|W_s] (+bm on dst half) -> bf16 ----------------
__global__ __launch_bounds__(256) void zdzs_kernel(
    const __bf16* __restrict__ hb, const __bf16* __restrict__ ZW,
    const float* __restrict__ bm, __bf16* __restrict__ z) {
  __shared__ __align__(16) __bf16 Bt[2][ZW_CHUNK];  // 32 KB
  int tid = threadIdx.x;
  int wid = tid >> 6, lane = tid & 63, m = lane & 31, half = lane >> 5;
  int nb = blockIdx.x * 128;
  int row = nb + wid * 32 + m;
  const __bf16* aH = hb + (size_t)row * H + half * 8;
  const short8* gW = (const short8*)ZW;  // 1024 short8 per chunk
  short8* sB0 = (short8*)&Bt[0][0];
  short8* sB1 = (short8*)&Bt[1][0];
#pragma unroll
  for (int q = 0; q < 4; ++q) sB0[tid + q * 256] = gW[tid + q * 256];
  short8 p0 = gW[1024 + tid], p1 = gW[1024 + tid + 256];
  short8 p2 = gW[1024 + tid + 512], p3 = gW[1024 + tid + 768];
  f32x16 acc[8];
#pragma unroll
  for (int nt = 0; nt < 8; ++nt)
#pragma unroll
    for (int r = 0; r < 16; ++r) acc[nt][r] = 0.f;
  bf16x8 a = *(const bf16x8*)aH;
  block_sync_lds();

  for (int s = 0; s < 8; ++s) {
    int buf = s & 1;
    bf16x8 na = a;
    if (s + 1 < 8) na = *(const bf16x8*)(aH + (s + 1) * 16);
    if (s + 1 < 8) {
      short8* sb = buf ? sB0 : sB1;
      sb[tid] = p0;
      sb[tid + 256] = p1;
      sb[tid + 512] = p2;
      sb[tid + 768] = p3;
      if (s + 2 < 8) {
        p0 = gW[(size_t)(s + 2) * 1024 + tid];
        p1 = gW[(size_t)(s + 2) * 1024 + tid + 256];
        p2 = gW[(size_t)(s + 2) * 1024 + tid + 512];
        p3 = gW[(size_t)(s + 2) * 1024 + tid + 768];
      }
    }
    const __bf16* bb = &Bt[buf][0];
#pragma unroll
    for (int nt = 0; nt < 8; ++nt) {
      bf16x8 bh = *(const bf16x8*)&bb[((0 * 8 + nt) * 64 + lane) * 8];
      bf16x8 bl = *(const bf16x8*)&bb[((1 * 8 + nt) * 64 + lane) * 8];
      acc[nt] = __builtin_amdgcn_mfma_f32_32x32x16_bf16(a, bh, acc[nt], 0, 0, 0);
      acc[nt] = __builtin_amdgcn_mfma_f32_32x32x16_bf16(a, bl, acc[nt], 0, 0, 0);
    }
    a = na;
    if (s + 1 < 8) block_sync_lds();
  }

  float bmv[4];
#pragma unroll
  for (int nt = 0; nt < 4; ++nt) bmv[nt] = bm[nt * 32 + m];
#pragma unroll
  for (int nt = 0; nt < 8; ++nt) {
    float bias = (nt < 4) ? bmv[nt] : 0.f;
#pragma unroll
    for (int r = 0; r < 16; ++r) {
      int rowi = (r & 3) + 8 * (r >> 2) + 4 * half;
      z[(size_t)(nb + wid * 32 + rowi) * 256 + nt * 32 + m] =
          (__bf16)(acc[nt][r] + bias);
    }
  }
}

// ---------------- zePre[e] = eaSrt[e] @ Wef : MFMA, K=16 ----------------
__global__ __launch_bounds__(256) void ze_kernel(
    const __bf16* __restrict__ eaSrt, const __bf16* __restrict__ WefS,
    __bf16* __restrict__ zePre) {
  __shared__ __align__(16) __bf16 Bf[CHUNK_ELEMS];  // 8 KB
  int tid = threadIdx.x;
  ((short8*)Bf)[tid] = ((const short8*)WefS)[tid];
  ((short8*)Bf)[tid + 256] = ((const short8*)WefS)[tid + 256];
  int wid = tid >> 6, lane = tid & 63, m = lane & 31, half = lane >> 5;
  int ebase = blockIdx.x * ZEB + wid * 32;
  bf16x8 a = *(const bf16x8*)(eaSrt + (size_t)(ebase + m) * EDIM + half * 8);
  f32x16 acc[4];
#pragma unroll
  for (int nt = 0; nt < 4; ++nt)
#pragma unroll
    for (int r = 0; r < 16; ++r) acc[nt][r] = 0.f;
  block_sync_lds();
#pragma unroll
  for (int nt = 0; nt < 4; ++nt) {
    bf16x8 bh = *(const bf16x8*)&Bf[((0 * 4 + nt) * 64 + lane) * 8];
    bf16x8 bl = *(const bf16x8*)&Bf[((1 * 4 + nt) * 64 + lane) * 8];
    acc[nt] = __builtin_amdgcn_mfma_f32_32x32x16_bf16(a, bh, acc[nt], 0, 0, 0);
    acc[nt] = __builtin_amdgcn_mfma_f32_32x32x16_bf16(a, bl, acc[nt], 0, 0, 0);
  }
#pragma unroll
  for (int nt = 0; nt < 4; ++nt) {
#pragma unroll
    for (int r = 0; r < 16; ++r) {
      int rowi = (r & 3) + 8 * (r >> 2) + 4 * half;
      zePre[(size_t)(ebase + rowi) * H + nt * 32 + m] = (__bf16)acc[nt][r];
    }
  }
}

// ---------------- node-parallel CSR aggregation: aggr[n] = sum relu(zd+zs+ze) ----------------
// one wave per node; 4-deep load batching (4 z_s + 4 ze in flight, next srcs
// prefetched a group ahead); plain coalesced store, no atomics.
__global__ __launch_bounds__(256) void edge_aggr_kernel(
    const __bf16* __restrict__ z, const int* __restrict__ srcSrt,
    const int* __restrict__ cend, const __bf16* __restrict__ zePre,
    float* __restrict__ aggrH) {
  int node = blockIdx.x * 4 + (threadIdx.x >> 6);
  int lane = threadIdx.x & 63;
  int c0 = lane * 2;
  int end = cend[node];
  int start = node ? cend[node - 1] : 0;
  v2f acc = {0.f, 0.f};
  if (start < end) {
    v2f zd = bf2f(*(const unsigned*)(z + (size_t)node * 256 + c0));
    int sArr[4];
#pragma unroll
    for (int p = 0; p < 4; ++p)
      if (start + p < end) sArr[p] = srcSrt[start + p];
    for (int e0 = start; e0 < end; e0 += 4) {
      unsigned zsb[4], zeb[4];
#pragma unroll
      for (int p = 0; p < 4; ++p) {
        if (e0 + p < end) {
          zsb[p] = *(const unsigned*)(z + (size_t)sArr[p] * 256 + 128 + c0);
          zeb[p] = *(const unsigned*)(zePre + (size_t)(e0 + p) * H + c0);
        }
      }
#pragma unroll
      for (int p = 0; p < 4; ++p)
        if (e0 + 4 + p < end) sArr[p] = srcSrt[e0 + 4 + p];
#pragma unroll
      for (int p = 0; p < 4; ++p) {
        if (e0 + p < end) {
          v2f t = zd + bf2f(zsb[p]) + bf2f(zeb[p]);
          acc.x += fmaxf(t.x, 0.f);
          acc.y += fmaxf(t.y, 0.f);
        }
      }
    }
  }
  *(v2f*)(aggrH + (size_t)node * H + c0) = acc;
}

// ---------------- MFMA fused node update (h bf16) ----------------
__global__ __launch_bounds__(256) void node_update_mfma_kernel(
    __bf16* __restrict__ hb, const float* __restrict__ aggrH,
    const int* __restrict__ deg, const __bf16* __restrict__ WnS,
    const float* __restrict__ ub1, const float* __restrict__ va,
    const float* __restrict__ ub2) {
  __shared__ __align__(16) __bf16 Bt[2][CHUNK_ELEMS];
  __shared__ __bf16 hid[4][32][132];
  __shared__ float degS[128];
  int tid = threadIdx.x;
  int nb = blockIdx.x * 128;
  if (tid < 128) degS[tid] = (float)deg[nb + tid];
  int wid = tid >> 6, lane = tid & 63, m = lane & 31, half = lane >> 5;
  int row = nb + wid * 32 + m;
  const __bf16* aHb = hb + (size_t)row * H + half * 8;
  const float* aG = aggrH + (size_t)row * H + half * 8;
  const short8* gW = (const short8*)WnS;
  short8* sB0 = (short8*)&Bt[0][0];
  short8* sB1 = (short8*)&Bt[1][0];
  sB0[tid] = gW[tid];
  sB0[tid + 256] = gW[tid + 256];
  short8 p0 = gW[512 + tid], p1 = gW[512 + tid + 256];
  float bv1[4], bva[4];
#pragma unroll
  for (int nt = 0; nt < 4; ++nt) {
    bv1[nt] = ub1[nt * 32 + m];
    bva[nt] = va[nt * 32 + m];
  }
  f32x16 acc[4];
#pragma unroll
  for (int nt = 0; nt < 4; ++nt)
#pragma unroll
    for (int r = 0; r < 16; ++r) acc[nt][r] = 0.f;
  bf16x8 acur = *(const bf16x8*)aHb;
  block_sync_lds();

  for (int s = 0; s < 16; ++s) {
    int buf = s & 1;
    bf16x8 anext = acur;
    if (s + 1 < 16) {
      int sp = s + 1;
      if (sp < 8) {
        anext = *(const bf16x8*)(aHb + sp * 16);
      } else {
        const float* pp = aG + (sp - 8) * 16;
        float4 f0 = *(const float4*)pp;
        float4 f1 = *(const float4*)(pp + 4);
        float af[8] = {f0.x, f0.y, f0.z, f0.w, f1.x, f1.y, f1.z, f1.w};
#pragma unroll
        for (int j = 0; j < 8; ++j) anext[j] = (__bf16)af[j];
      }
    }
    {
      short8* sb = buf ? sB0 : sB1;
      sb[tid] = p0;
      sb[tid + 256] = p1;
      if (s + 2 < NODE_CHUNKS) {
        p0 = gW[(size_t)(s + 2) * 512 + tid];
        p1 = gW[(size_t)(s + 2) * 512 + tid + 256];
      }
    }
    const __bf16* bb = &Bt[buf][0];
#pragma unroll
    for (int nt = 0; nt < 4; ++nt) {
      bf16x8 bh = *(const bf16x8*)&bb[((0 * 4 + nt) * 64 + lane) * 8];
      bf16x8 bl = *(const bf16x8*)&bb[((1 * 4 + nt) * 64 + lane) * 8];
      acc[nt] = __builtin_amdgcn_mfma_f32_32x32x16_bf16(acur, bh, acc[nt], 0, 0, 0);
      acc[nt] = __builtin_amdgcn_mfma_f32_32x32x16_bf16(acur, bl, acc[nt], 0, 0, 0);
    }
    acur = anext;
    block_sync_lds();
  }

#pragma unroll
  for (int nt = 0; nt < 4; ++nt) {
#pragma unroll
    for (int r = 0; r < 16; ++r) {
      int rowi = (r & 3) + 8 * (r >> 2) + 4 * half;
      float v = acc[nt][r] + bv1[nt] + degS[wid * 32 + rowi] * bva[nt];
      hid[wid][rowi][nt * 32 + m] = (__bf16)fmaxf(v, 0.f);
      acc[nt][r] = 0.f;
    }
  }
  wait_lds();

  for (int s = 16; s < NODE_CHUNKS; ++s) {
    int buf = s & 1;
    if (s + 1 < NODE_CHUNKS) {
      short8* sb = buf ? sB0 : sB1;
      sb[tid] = p0;
      sb[tid + 256] = p1;
      if (s + 2 < NODE_CHUNKS) {
        p0 = gW[(size_t)(s + 2) * 512 + tid];
        p1 = gW[(size_t)(s + 2) * 512 + tid + 256];
      }
    }
    bf16x8 ah = *(const bf16x8*)&hid[wid][m][(s - 16) * 16 + half * 8];
    const __bf16* bb = &Bt[buf][0];
#pragma unroll
    for (int nt = 0; nt < 4; ++nt) {
      bf16x8 bh = *(const bf16x8*)&bb[((0 * 4 + nt) * 64 + lane) * 8];
      bf16x8 bl = *(const bf16x8*)&bb[((1 * 4 + nt) * 64 + lane) * 8];
      acc[nt] = __builtin_amdgcn_mfma_f32_32x32x16_bf16(ah, bh, acc[nt], 0, 0, 0);
      acc[nt] = __builtin_amdgcn_mfma_f32_32x32x16_bf16(ah, bl, acc[nt], 0, 0, 0);
    }
    if (s + 1 < NODE_CHUNKS) block_sync_lds();
  }

#pragma unroll
  for (int nt = 0; nt < 4; ++nt) {
    float b2 = ub2[nt * 32 + m];
#pragma unroll
    for (int r = 0; r < 16; ++r) {
      int rowi = (r & 3) + 8 * (r >> 2) + 4 * half;
      size_t idx = (size_t)(nb + wid * 32 + rowi) * H + nt * 32 + m;
      float hv = (float)hb[idx];
      hb[idx] = (__bf16)(hv + acc[nt][r] + b2);
    }
  }
}

// ---------------- batch mean pooling (batch is sorted) ----------------
__global__ __launch_bounds__(128) void pool_kernel(
    const __bf16* __restrict__ hb, const int* __restrict__ batch,
    float* __restrict__ pooled, int* __restrict__ counts) {
  int j = threadIdx.x;
  int nbase = blockIdx.x * 128;
  int nend = nbase + 128;
  if (nend > NN) nend = NN;
  if (nbase >= NN) return;
  int cur = batch[nbase];
  float sum = 0.f;
  int cnt = 0;
  for (int n = nbase; n < nend; ++n) {
    int b = batch[n];
    if (b != cur) {
      unsafeAtomicAdd(&pooled[cur * H + j], sum);
      if (j == 0) atomicAdd(&counts[cur], cnt);
      sum = 0.f; cnt = 0; cur = b;
    }
    sum += (float)hb[(size_t)n * H + j];
    cnt++;
  }
  unsafeAtomicAdd(&pooled[cur * H + j], sum);
  if (j == 0) atomicAdd(&counts[cur], cnt);
}

// ---------------- readout MLP ----------------
__global__ __launch_bounds__(128) void readout_kernel(
    const float* __restrict__ pooled, const int* __restrict__ counts,
    const float* __restrict__ gf, const float* __restrict__ Wg,
    const float* __restrict__ bg, const float* __restrict__ rW1,
    const float* __restrict__ rb1, const float* __restrict__ rW2,
    const float* __restrict__ rb2, const float* __restrict__ rW3,
    const float* __restrict__ rb3, float* __restrict__ out) {
  __shared__ float fin[256];
  __shared__ float t1[128];
  __shared__ float t2[64];
  int j = threadIdx.x;
  for (int b = 0; b < NBATCH; ++b) {
    float cnt = (float)counts[b];
    if (cnt < 1.f) cnt = 1.f;
    fin[j] = pooled[b * H + j] / cnt;
    fin[H + j] = fmaf(gf[b], Wg[j], bg[j]);
    __syncthreads();
    float a = rb1[j];
    for (int k = 0; k < 256; ++k) a = fmaf(fin[k], rW1[k * H + j], a);
    t1[j] = fmaxf(a, 0.f);
    __syncthreads();
    if (j < 64) {
      float a2 = rb2[j];
      for (int k = 0; k < 128; ++k) a2 = fmaf(t1[k], rW2[k * 64 + j], a2);
      t2[j] = fmaxf(a2, 0.f);
    }
    __syncthreads();
    if (j < 64) {
      float p = t2[j] * rW3[j];
#pragma unroll
      for (int off = 32; off; off >>= 1) p += __shfl_down(p, off);
      if (j == 0) out[b] = p + rb3[0];
    }
    __syncthreads();
  }
}

extern "C" void kernel_launch(void* const* d_in, const int* in_sizes, int n_in,
                              void* d_out, int out_size, void* d_ws, size_t ws_size,
                              hipStream_t stream) {
  const float* x   = (const float*)d_in[0];
  const float* ea  = (const float*)d_in[1];
  const float* gf  = (const float*)d_in[2];
  const int*   ei  = (const int*)d_in[3];
  const int*   bat = (const int*)d_in[4];
  const float* Wn  = (const float*)d_in[5];
  const float* bn  = (const float*)d_in[6];
  const float* We  = (const float*)d_in[7];
  const float* be  = (const float*)d_in[8];
  const float* Wg  = (const float*)d_in[9];
  const float* bg  = (const float*)d_in[10];
  const float* mW1 = (const float*)d_in[11];
  const float* mb1 = (const float*)d_in[12];
  const float* mW2 = (const float*)d_in[13];
  const float* mb2 = (const float*)d_in[14];
  const float* uW1 = (const float*)d_in[15];
  const float* ub1 = (const float*)d_in[16];
  const float* uW2 = (const float*)d_in[17];
  const float* ub2 = (const float*)d_in[18];
  const float* rW1 = (const float*)d_in[19];
  const float* rb1 = (const float*)d_in[20];
  const float* rW2 = (const float*)d_in[21];
  const float* rb2 = (const float*)d_in[22];
  const float* rW3 = (const float*)d_in[23];
  const float* rb3 = (const float*)d_in[24];

  char* p = (char*)d_ws;
  __bf16* hb     = (__bf16*)p; p += (size_t)NPAD * H * 2;        // 12.8 MB
  float*  aggrH  = (float*)p;  p += (size_t)NPAD * H * 4;        // 25.6 MB
  __bf16* z      = (__bf16*)p; p += (size_t)NPAD * 256 * 2;      // 25.6 MB
  __bf16* zePre  = (__bf16*)p; p += (size_t)NE * H * 2;          // 102.4 MB
  __bf16* eaSrt  = (__bf16*)p; p += (size_t)NE * EDIM * 2;       // 12.8 MB
  int*    srcSrt = (int*)p;    p += (size_t)NE * 4;
  int*    eidSrt = (int*)p;    p += (size_t)NE * 4;
  __bf16* ZW     = (__bf16*)p; p += (size_t)NLAYERS * 8 * ZW_CHUNK * 2;
  __bf16* WnS    = (__bf16*)p; p += (size_t)NLAYERS * NODE_CHUNKS * CHUNK_ELEMS * 2;
  __bf16* WefS   = (__bf16*)p; p += (size_t)NLAYERS * CHUNK_ELEMS * 2;
  float*  Wef    = (float*)p;  p += (size_t)NLAYERS * EDIM * H * 4;
  float*  bm     = (float*)p;  p += (size_t)NLAYERS * H * 4;
  float*  Wu     = (float*)p;  p += (size_t)NLAYERS * 256 * H * 4;
  float*  va     = (float*)p;  p += (size_t)NLAYERS * H * 4;
  int*    deg    = (int*)p;    p += (size_t)NPAD * 4;
  int*    cursor = (int*)p;    p += (size_t)NPAD * 4;
  int*    bsum   = (int*)p;    p += 256 * 4;
  int*    boff   = (int*)p;    p += 256 * 4;
  float*  pooled = (float*)p;  p += (size_t)NBATCH * H * 4;
  int*    counts = (int*)p;    p += 64;

  hipMemsetAsync(deg, 0, (size_t)NPAD * 4, stream);
  hipMemsetAsync(cursor, 0, (size_t)NPAD * 4, stream);  // tail stays 0 -> empty segments for pad nodes
  hipMemsetAsync(pooled, 0, (size_t)NBATCH * H * 4, stream);
  hipMemsetAsync(counts, 0, 64, stream);

  embed_nodes_kernel<<<NN / 16, 128, 0, stream>>>(x, Wn, bn, hb);
  degree_kernel<<<(NE + 255) / 256, 256, 0, stream>>>(ei, deg);
  scan1_kernel<<<NSB, 256, 0, stream>>>(deg, bsum);
  scan2_kernel<<<1, 256, 0, stream>>>(bsum, boff);
  scan3_kernel<<<NSB, 256, 0, stream>>>(deg, boff, cursor);
  scatter_kernel<<<(NE + 255) / 256, 256, 0, stream>>>(ei, cursor, srcSrt, eidSrt);
  gather_ea_kernel<<<(NE + 255) / 256, 256, 0, stream>>>(ea, eidSrt, eaSrt);
  precomp_zw_kernel<<<NLAYERS * 8, 256, 0, stream>>>(mW1, ZW);
  precomp_wef_kernel<<<NLAYERS, 128, 0, stream>>>(mW1, mb1, We, be, Wef, bm);
  precomp_wefs_kernel<<<NLAYERS, 256, 0, stream>>>(Wef, WefS);
  precomp_wu_kernel<<<NLAYERS * 257, 128, 0, stream>>>(uW1, mW2, mb2, Wu, va);
  precomp_wns_kernel<<<NLAYERS * NODE_CHUNKS, 256, 0, stream>>>(Wu, uW2, WnS);

  for (int l = 0; l < NLAYERS; ++l) {
    zdzs_kernel<<<NBLK, 256, 0, stream>>>(
        hb, ZW + (size_t)l * 8 * ZW_CHUNK, bm + (size_t)l * H, z);
    ze_kernel<<<NE / ZEB, 256, 0, stream>>>(
        eaSrt, WefS + (size_t)l * CHUNK_ELEMS, zePre);
    edge_aggr_kernel<<<NPAD / 4, 256, 0, stream>>>(
        z, srcSrt, cursor, zePre, aggrH);
    node_update_mfma_kernel<<<NBLK, 256, 0, stream>>>(
        hb, aggrH, deg, WnS + (size_t)l * NODE_CHUNKS * CHUNK_ELEMS,
        ub1 + (size_t)l * H, va + (size_t)l * H, ub2 + (size_t)l * H);
  }

  pool_kernel<<<(NN + 127) / 128, 128, 0, stream>>>(hb, bat, pooled, counts);
  readout_kernel<<<1, 128, 0, stream>>>(pooled, counts, gf, Wg, bg, rW1, rb1,
                                        rW2, rb2, rW3, rb3, (float*)d_out);
}

// Round 16
// 577.993 us; speedup vs baseline: 1.0782x; 1.0782x over previous
//
#include <hip/hip_runtime.h>

#define NN 50000
#define NPAD 50048     // 391 * 128
#define NBLK 391
#define NE 400000
#define NBATCH 8
#define NDIM 32
#define EDIM 16
#define H 128
#define NLAYERS 3
#define CHUNK_ELEMS 4096   // node-kernel weight chunk: 2 hilo * 4 nt * 64 lane * 8
#define NODE_CHUNKS 24     // 16 (Wu, K=256) + 8 (uW2, K=128)
#define ZW_CHUNK 8192      // zdzs chunk: 2 hilo * 8 nt * 64 lane * 8
#define NSB 196            // scan blocks: ceil(50000/256)
#define ZEB 128            // edges per block in ze_kernel (4 waves x 32)

typedef __attribute__((ext_vector_type(8))) __bf16 bf16x8;
typedef __attribute__((ext_vector_type(16))) float f32x16;
typedef __attribute__((ext_vector_type(8))) short short8;
typedef __attribute__((ext_vector_type(2))) float v2f;

__device__ __forceinline__ void block_sync_lds() {
  asm volatile("s_waitcnt lgkmcnt(0)\ns_barrier" ::: "memory");
}
__device__ __forceinline__ void wait_lds() {
  asm volatile("s_waitcnt lgkmcnt(0)" ::: "memory");
}
// one dword = 2 packed bf16 -> 2 fp32 (pure bit ops)
__device__ __forceinline__ v2f bf2f(unsigned u) {
  v2f r;
  r.x = __uint_as_float(u << 16);
  r.y = __uint_as_float(u & 0xffff0000u);
  return r;
}

// ---------------- node embedding: h = x @ Wn + bn (bf16 out) ----------------
__global__ __launch_bounds__(128) void embed_nodes_kernel(
    const float* __restrict__ x, const float* __restrict__ Wn,
    const float* __restrict__ bn, __bf16* __restrict__ hb) {
  __shared__ float Ws[NDIM * H];
  __shared__ float xs[16 * NDIM];
  int j = threadIdx.x;
  int nbase = blockIdx.x * 16;
  for (int r = 0; r < NDIM; ++r) Ws[r * H + j] = Wn[r * H + j];
#pragma unroll
  for (int t = 0; t < 4; ++t) {
    int f = j + t * 128;
    xs[f] = x[nbase * NDIM + f];
  }
  __syncthreads();
  float b = bn[j];
  for (int nn = 0; nn < 16; ++nn) {
    float acc = b;
#pragma unroll
    for (int k = 0; k < NDIM; ++k)
      acc = fmaf(xs[nn * NDIM + k], Ws[k * H + j], acc);
    hb[(size_t)(nbase + nn) * H + j] = (__bf16)acc;
  }
}

// ---------------- degree histogram over dst ----------------
__global__ __launch_bounds__(256) void degree_kernel(const int* __restrict__ ei,
                                                     int* __restrict__ deg) {
  int e = blockIdx.x * 256 + threadIdx.x;
  if (e < NE) atomicAdd(&deg[ei[NE + e]], 1);
}

// ---------------- parallel 3-phase exclusive scan of deg -> cursor ----------------
__global__ __launch_bounds__(256) void scan1_kernel(const int* __restrict__ deg,
                                                    int* __restrict__ bsum) {
  __shared__ int ws[4];
  int i = blockIdx.x * 256 + threadIdx.x;
  int lane = threadIdx.x & 63, wid = threadIdx.x >> 6;
  int v = (i < NN) ? deg[i] : 0;
#pragma unroll
  for (int off = 32; off; off >>= 1) v += __shfl_down(v, off);
  if (lane == 0) ws[wid] = v;
  __syncthreads();
  if (threadIdx.x == 0) bsum[blockIdx.x] = ws[0] + ws[1] + ws[2] + ws[3];
}

__global__ __launch_bounds__(256) void scan2_kernel(const int* __restrict__ bsum,
                                                    int* __restrict__ boff) {
  __shared__ int s[256];
  int t = threadIdx.x;
  int v = (t < NSB) ? bsum[t] : 0;
  s[t] = v;
  __syncthreads();
  for (int off = 1; off < 256; off <<= 1) {
    int u = (t >= off) ? s[t - off] : 0;
    __syncthreads();
    s[t] += u;
    __syncthreads();
  }
  if (t < NSB) boff[t] = s[t] - v;  // exclusive across blocks
}

__global__ __launch_bounds__(256) void scan3_kernel(const int* __restrict__ deg,
                                                    const int* __restrict__ boff,
                                                    int* __restrict__ cursor) {
  __shared__ int wsum[4], woff[4];
  int i = blockIdx.x * 256 + threadIdx.x;
  int lane = threadIdx.x & 63, wid = threadIdx.x >> 6;
  int orig = (i < NN) ? deg[i] : 0;
  int v = orig;
#pragma unroll
  for (int off = 1; off < 64; off <<= 1) {
    int u = __shfl_up(v, off);
    if (lane >= off) v += u;
  }
  if (lane == 63) wsum[wid] = v;
  __syncthreads();
  if (threadIdx.x == 0) {
    int r = 0;
#pragma unroll
    for (int w = 0; w < 4; ++w) {
      woff[w] = r;
      r += wsum[w];
    }
  }
  __syncthreads();
  if (i < NN) cursor[i] = (v - orig) + woff[wid] + boff[blockIdx.x];
}

// ---------------- counting-sort scatter: edges grouped by dst ----------------
// after this kernel, cursor[n] == END offset of node n's segment (CSR rowptr).
__global__ __launch_bounds__(256) void scatter_kernel(
    const int* __restrict__ ei, int* __restrict__ cursor,
    int* __restrict__ srcSrt, int* __restrict__ eidSrt) {
  int e = blockIdx.x * 256 + threadIdx.x;
  if (e < NE) {
    int d = ei[NE + e];
    int pos = atomicAdd(&cursor[d], 1);
    srcSrt[pos] = ei[e];
    eidSrt[pos] = e;
  }
}

// ---------------- gather edge attrs into sorted order, fp32 -> bf16 (once) ----------------
__global__ __launch_bounds__(256) void gather_ea_kernel(
    const float* __restrict__ ea, const int* __restrict__ eidSrt,
    __bf16* __restrict__ eaSrt) {
  int fl = blockIdx.x * 256 + threadIdx.x;
  if (fl < NE) {
    int e = eidSrt[fl];
    const float4* ep = (const float4*)(ea + (size_t)e * EDIM);
    __bf16* op = eaSrt + (size_t)fl * EDIM;
#pragma unroll
    for (int q = 0; q < 4; ++q) {
      float4 v = ep[q];
      op[q * 4 + 0] = (__bf16)v.x;
      op[q * 4 + 1] = (__bf16)v.y;
      op[q * 4 + 2] = (__bf16)v.z;
      op[q * 4 + 3] = (__bf16)v.w;
    }
  }
}

// ---------------- zdzs weights: mW1[0:256] -> hi/lo bf16, frag-swizzled ----------------
__global__ __launch_bounds__(256) void precomp_zw_kernel(
    const float* __restrict__ mW1, __bf16* __restrict__ ZW) {
  int l = blockIdx.x / 8;
  int c = blockIdx.x % 8;
  int tid = threadIdx.x;
  const float* w1 = mW1 + (size_t)l * 384 * H;
  __bf16* dst = ZW + ((size_t)l * 8 + c) * ZW_CHUNK;
  for (int it = 0; it < 32; ++it) {
    int flat = it * 256 + tid;
    int j = flat & 7;
    int lane = (flat >> 3) & 63;
    int nt = (flat >> 9) & 7;
    int hilo = flat >> 12;
    int k = c * 16 + ((lane >> 5) << 3) + j;
    int n = nt * 32 + (lane & 31);
    float w = (n < 128) ? w1[(size_t)k * H + n]
                        : w1[(size_t)(128 + k) * H + (n - 128)];
    __bf16 hi = (__bf16)w;
    __bf16 lo = (__bf16)(w - (float)hi);
    dst[flat] = hilo ? lo : hi;
  }
}

// ---------------- Wef = We @ mW1[256:384] (16x128), bm = mb1 + be @ ... ----------------
__global__ __launch_bounds__(128) void precomp_wef_kernel(
    const float* __restrict__ mW1, const float* __restrict__ mb1,
    const float* __restrict__ We, const float* __restrict__ be,
    float* __restrict__ Wef, float* __restrict__ bm) {
  int l = blockIdx.x;
  int n = threadIdx.x;
  const float* w1 = mW1 + (size_t)l * 384 * H;
  float acc[EDIM];
#pragma unroll
  for (int i = 0; i < EDIM; ++i) acc[i] = 0.f;
  float accb = 0.f;
  for (int c = 0; c < H; ++c) {
    float wv = w1[(size_t)(256 + c) * H + n];
    accb = fmaf(be[c], wv, accb);
#pragma unroll
    for (int i = 0; i < EDIM; ++i)
      acc[i] = fmaf(We[i * H + c], wv, acc[i]);
  }
#pragma unroll
  for (int i = 0; i < EDIM; ++i)
    Wef[((size_t)l * EDIM + i) * H + n] = acc[i];
  bm[l * H + n] = mb1[l * H + n] + accb;
}

// ---------------- swizzle Wef into MFMA frag order (hi/lo), K=16 ----------------
__global__ __launch_bounds__(256) void precomp_wefs_kernel(
    const float* __restrict__ Wef, __bf16* __restrict__ WefS) {
  int l = blockIdx.x;
  int tid = threadIdx.x;
  int nt = tid >> 6, lane = tid & 63;
  int n = nt * 32 + (lane & 31);
  int half = lane >> 5;
  const float* wl = Wef + (size_t)l * EDIM * H;
  __bf16* dst = WefS + (size_t)l * CHUNK_ELEMS;
#pragma unroll
  for (int j = 0; j < 8; ++j) {
    int k = half * 8 + j;
    float w = wl[(size_t)k * H + n];
    __bf16 hi = (__bf16)w;
    __bf16 lo = (__bf16)(w - (float)hi);
    dst[((0 * 4 + nt) * 64 + lane) * 8 + j] = hi;
    dst[((1 * 4 + nt) * 64 + lane) * 8 + j] = lo;
  }
}

// ---------------- precompute folded update weights (fp32 Wu) ----------------
__global__ __launch_bounds__(128) void precomp_wu_kernel(
    const float* __restrict__ uW1, const float* __restrict__ mW2,
    const float* __restrict__ mb2, float* __restrict__ Wu,
    float* __restrict__ va) {
  int l = blockIdx.x / 257;
  int r = blockIdx.x % 257;
  int j = threadIdx.x;
  const float* u1 = uW1 + (size_t)l * 256 * H;
  if (r < 128) {
    Wu[((size_t)l * 256 + r) * H + j] = u1[(size_t)r * H + j];
  } else if (r < 256) {
    int i = r - 128;
    const float* m2 = mW2 + ((size_t)l * H + i) * H;
    float s = 0.f;
    for (int c = 0; c < H; ++c)
      s = fmaf(m2[c], u1[(size_t)(128 + c) * H + j], s);
    Wu[((size_t)l * 256 + r) * H + j] = s;
  } else {
    float s = 0.f;
    for (int c = 0; c < H; ++c)
      s = fmaf(mb2[l * H + c], u1[(size_t)(128 + c) * H + j], s);
    va[l * H + j] = s;
  }
}

// ---------------- swizzle node weights into hi/lo frag chunks ----------------
__global__ __launch_bounds__(256) void precomp_wns_kernel(
    const float* __restrict__ Wu, const float* __restrict__ uW2,
    __bf16* __restrict__ WnS) {
  int l = blockIdx.x / NODE_CHUNKS;
  int c = blockIdx.x % NODE_CHUNKS;
  int tid = threadIdx.x;
  int nt = tid >> 6, lane = tid & 63;
  int n = nt * 32 + (lane & 31);
  int half = lane >> 5;
  __bf16* dst = WnS + ((size_t)l * NODE_CHUNKS + c) * CHUNK_ELEMS;
#pragma unroll
  for (int j = 0; j < 8; ++j) {
    float w;
    if (c < 16) {
      int k = c * 16 + half * 8 + j;
      w = Wu[((size_t)l * 256 + k) * H + n];
    } else {
      int k = (c - 16) * 16 + half * 8 + j;
      w = uW2[((size_t)l * H + k) * H + n];
    }
    __bf16 hi = (__bf16)w;
    __bf16 lo = (__bf16)(w - (float)hi);
    dst[((0 * 4 + nt) * 64 + lane) * 8 + j] = hi;
    dst[((1 * 4 + nt) * 64 + lane) * 8 + j] = lo;
  }
}

// ---------------- z = h @ [W_d|W_s] (+bm on dst half) -> bf16 ----------------
__global__ __launch_bounds__(256) void zdzs_kernel(
    const __bf16* __restrict__ hb, const __bf16* __restrict__ ZW,
    const float* __restrict__ bm, __bf16* __restrict__ z) {
  __shared__ __align__(16) __bf16 Bt[2][ZW_CHUNK];  // 32 KB
  int tid = threadIdx.x;
  int wid = tid >> 6, lane = tid & 63, m = lane & 31, half = lane >> 5;
  int nb = blockIdx.x * 128;
  int row = nb + wid * 32 + m;
  const __bf16* aH = hb + (size_t)row * H + half * 8;
  const short8* gW = (const short8*)ZW;  // 1024 short8 per chunk
  short8* sB0 = (short8*)&Bt[0][0];
  short8* sB1 = (short8*)&Bt[1][0];
#pragma unroll
  for (int q = 0; q < 4; ++q) sB0[tid + q * 256] = gW[tid + q * 256];
  short8 p0 = gW[1024 + tid], p1 = gW[1024 + tid + 256];
  short8 p2 = gW[1024 + tid + 512], p3 = gW[1024 + tid + 768];
  f32x16 acc[8];
#pragma unroll
  for (int nt = 0; nt < 8; ++nt)
#pragma unroll
    for (int r = 0; r < 16; ++r) acc[nt][r] = 0.f;
  bf16x8 a = *(const bf16x8*)aH;
  block_sync_lds();

  for (int s = 0; s < 8; ++s) {
    int buf = s & 1;
    bf16x8 na = a;
    if (s + 1 < 8) na = *(const bf16x8*)(aH + (s + 1) * 16);
    if (s + 1 < 8) {
      short8* sb = buf ? sB0 : sB1;
      sb[tid] = p0;
      sb[tid + 256] = p1;
      sb[tid + 512] = p2;
      sb[tid + 768] = p3;
      if (s + 2 < 8) {
        p0 = gW[(size_t)(s + 2) * 1024 + tid];
        p1 = gW[(size_t)(s + 2) * 1024 + tid + 256];
        p2 = gW[(size_t)(s + 2) * 1024 + tid + 512];
        p3 = gW[(size_t)(s + 2) * 1024 + tid + 768];
      }
    }
    const __bf16* bb = &Bt[buf][0];
#pragma unroll
    for (int nt = 0; nt < 8; ++nt) {
      bf16x8 bh = *(const bf16x8*)&bb[((0 * 8 + nt) * 64 + lane) * 8];
      bf16x8 bl = *(const bf16x8*)&bb[((1 * 8 + nt) * 64 + lane) * 8];
      acc[nt] = __builtin_amdgcn_mfma_f32_32x32x16_bf16(a, bh, acc[nt], 0, 0, 0);
      acc[nt] = __builtin_amdgcn_mfma_f32_32x32x16_bf16(a, bl, acc[nt], 0, 0, 0);
    }
    a = na;
    if (s + 1 < 8) block_sync_lds();
  }

  float bmv[4];
#pragma unroll
  for (int nt = 0; nt < 4; ++nt) bmv[nt] = bm[nt * 32 + m];
#pragma unroll
  for (int nt = 0; nt < 8; ++nt) {
    float bias = (nt < 4) ? bmv[nt] : 0.f;
#pragma unroll
    for (int r = 0; r < 16; ++r) {
      int rowi = (r & 3) + 8 * (r >> 2) + 4 * half;
      z[(size_t)(nb + wid * 32 + rowi) * 256 + nt * 32 + m] =
          (__bf16)(acc[nt][r] + bias);
    }
  }
}

// ---------------- zePre[e] = eaSrt[e] @ Wef : MFMA, K=16 ----------------
__global__ __launch_bounds__(256) void ze_kernel(
    const __bf16* __restrict__ eaSrt, const __bf16* __restrict__ WefS,
    __bf16* __restrict__ zePre) {
  __shared__ __align__(16) __bf16 Bf[CHUNK_ELEMS];  // 8 KB
  int tid = threadIdx.x;
  ((short8*)Bf)[tid] = ((const short8*)WefS)[tid];
  ((short8*)Bf)[tid + 256] = ((const short8*)WefS)[tid + 256];
  int wid = tid >> 6, lane = tid & 63, m = lane & 31, half = lane >> 5;
  int ebase = blockIdx.x * ZEB + wid * 32;
  bf16x8 a = *(const bf16x8*)(eaSrt + (size_t)(ebase + m) * EDIM + half * 8);
  f32x16 acc[4];
#pragma unroll
  for (int nt = 0; nt < 4; ++nt)
#pragma unroll
    for (int r = 0; r < 16; ++r) acc[nt][r] = 0.f;
  block_sync_lds();
#pragma unroll
  for (int nt = 0; nt < 4; ++nt) {
    bf16x8 bh = *(const bf16x8*)&Bf[((0 * 4 + nt) * 64 + lane) * 8];
    bf16x8 bl = *(const bf16x8*)&Bf[((1 * 4 + nt) * 64 + lane) * 8];
    acc[nt] = __builtin_amdgcn_mfma_f32_32x32x16_bf16(a, bh, acc[nt], 0, 0, 0);
    acc[nt] = __builtin_amdgcn_mfma_f32_32x32x16_bf16(a, bl, acc[nt], 0, 0, 0);
  }
#pragma unroll
  for (int nt = 0; nt < 4; ++nt) {
#pragma unroll
    for (int r = 0; r < 16; ++r) {
      int rowi = (r & 3) + 8 * (r >> 2) + 4 * half;
      zePre[(size_t)(ebase + rowi) * H + nt * 32 + m] = (__bf16)acc[nt][r];
    }
  }
}

// ---------------- node-parallel CSR aggregation: aggr[n] = sum relu(zd+zs+ze) ----------------
__global__ __launch_bounds__(256) void edge_aggr_kernel(
    const __bf16* __restrict__ z, const int* __restrict__ srcSrt,
    const int* __restrict__ cend, const __bf16* __restrict__ zePre,
    float* __restrict__ aggrH) {
  int node = blockIdx.x * 4 + (threadIdx.x >> 6);
  int lane = threadIdx.x & 63;
  int c0 = lane * 2;
  int end = cend[node];
  int start = node ? cend[node - 1] : 0;
  v2f acc = {0.f, 0.f};
  if (start < end) {
    v2f zd = bf2f(*(const unsigned*)(z + (size_t)node * 256 + c0));
    int sArr[4];
#pragma unroll
    for (int p = 0; p < 4; ++p)
      if (start + p < end) sArr[p] = srcSrt[start + p];
    for (int e0 = start; e0 < end; e0 += 4) {
      unsigned zsb[4], zeb[4];
#pragma unroll
      for (int p = 0; p < 4; ++p) {
        if (e0 + p < end) {
          zsb[p] = *(const unsigned*)(z + (size_t)sArr[p] * 256 + 128 + c0);
          zeb[p] = *(const unsigned*)(zePre + (size_t)(e0 + p) * H + c0);
        }
      }
#pragma unroll
      for (int p = 0; p < 4; ++p)
        if (e0 + 4 + p < end) sArr[p] = srcSrt[e0 + 4 + p];
#pragma unroll
      for (int p = 0; p < 4; ++p) {
        if (e0 + p < end) {
          v2f t = zd + bf2f(zsb[p]) + bf2f(zeb[p]);
          acc.x += fmaxf(t.x, 0.f);
          acc.y += fmaxf(t.y, 0.f);
        }
      }
    }
  }
  *(v2f*)(aggrH + (size_t)node * H + c0) = acc;
}

// ---------------- MFMA fused node update (h bf16) ----------------
__global__ __launch_bounds__(256) void node_update_mfma_kernel(
    __bf16* __restrict__ hb, const float* __restrict__ aggrH,
    const int* __restrict__ deg, const __bf16* __restrict__ WnS,
    const float* __restrict__ ub1, const float* __restrict__ va,
    const float* __restrict__ ub2) {
  __shared__ __align__(16) __bf16 Bt[2][CHUNK_ELEMS];
  __shared__ __bf16 hid[4][32][132];
  __shared__ float degS[128];
  int tid = threadIdx.x;
  int nb = blockIdx.x * 128;
  if (tid < 128) degS[tid] = (float)deg[nb + tid];
  int wid = tid >> 6, lane = tid & 63, m = lane & 31, half = lane >> 5;
  int row = nb + wid * 32 + m;
  const __bf16* aHb = hb + (size_t)row * H + half * 8;
  const float* aG = aggrH + (size_t)row * H + half * 8;
  const short8* gW = (const short8*)WnS;
  short8* sB0 = (short8*)&Bt[0][0];
  short8* sB1 = (short8*)&Bt[1][0];
  sB0[tid] = gW[tid];
  sB0[tid + 256] = gW[tid + 256];
  short8 p0 = gW[512 + tid], p1 = gW[512 + tid + 256];
  float bv1[4], bva[4];
#pragma unroll
  for (int nt = 0; nt < 4; ++nt) {
    bv1[nt] = ub1[nt * 32 + m];
    bva[nt] = va[nt * 32 + m];
  }
  f32x16 acc[4];
#pragma unroll
  for (int nt = 0; nt < 4; ++nt)
#pragma unroll
    for (int r = 0; r < 16; ++r) acc[nt][r] = 0.f;
  bf16x8 acur = *(const bf16x8*)aHb;
  block_sync_lds();

  for (int s = 0; s < 16; ++s) {
    int buf = s & 1;
    bf16x8 anext = acur;
    if (s + 1 < 16) {
      int sp = s + 1;
      if (sp < 8) {
        anext = *(const bf16x8*)(aHb + sp * 16);
      } else {
        const float* pp = aG + (sp - 8) * 16;
        float4 f0 = *(const float4*)pp;
        float4 f1 = *(const float4*)(pp + 4);
        float af[8] = {f0.x, f0.y, f0.z, f0.w, f1.x, f1.y, f1.z, f1.w};
#pragma unroll
        for (int j = 0; j < 8; ++j) anext[j] = (__bf16)af[j];
      }
    }
    {
      short8* sb = buf ? sB0 : sB1;
      sb[tid] = p0;
      sb[tid + 256] = p1;
      if (s + 2 < NODE_CHUNKS) {
        p0 = gW[(size_t)(s + 2) * 512 + tid];
        p1 = gW[(size_t)(s + 2) * 512 + tid + 256];
      }
    }
    const __bf16* bb = &Bt[buf][0];
#pragma unroll
    for (int nt = 0; nt < 4; ++nt) {
      bf16x8 bh = *(const bf16x8*)&bb[((0 * 4 + nt) * 64 + lane) * 8];
      bf16x8 bl = *(const bf16x8*)&bb[((1 * 4 + nt) * 64 + lane) * 8];
      acc[nt] = __builtin_amdgcn_mfma_f32_32x32x16_bf16(acur, bh, acc[nt], 0, 0, 0);
      acc[nt] = __builtin_amdgcn_mfma_f32_32x32x16_bf16(acur, bl, acc[nt], 0, 0, 0);
    }
    acur = anext;
    block_sync_lds();
  }

#pragma unroll
  for (int nt = 0; nt < 4; ++nt) {
#pragma unroll
    for (int r = 0; r < 16; ++r) {
      int rowi = (r & 3) + 8 * (r >> 2) + 4 * half;
      float v = acc[nt][r] + bv1[nt] + degS[wid * 32 + rowi] * bva[nt];
      hid[wid][rowi][nt * 32 + m] = (__bf16)fmaxf(v, 0.f);
      acc[nt][r] = 0.f;
    }
  }
  wait_lds();

  for (int s = 16; s < NODE_CHUNKS; ++s) {
    int buf = s & 1;
    if (s + 1 < NODE_CHUNKS) {
      short8* sb = buf ? sB0 : sB1;
      sb[tid] = p0;
      sb[tid + 256] = p1;
      if (s + 2 < NODE_CHUNKS) {
        p0 = gW[(size_t)(s + 2) * 512 + tid];
        p1 = gW[(size_t)(s + 2) * 512 + tid + 256];
      }
    }
    bf16x8 ah = *(const bf16x8*)&hid[wid][m][(s - 16) * 16 + half * 8];
    const __bf16* bb = &Bt[buf][0];
#pragma unroll
    for (int nt = 0; nt < 4; ++nt) {
      bf16x8 bh = *(const bf16x8*)&bb[((0 * 4 + nt) * 64 + lane) * 8];
      bf16x8 bl = *(const bf16x8*)&bb[((1 * 4 + nt) * 64 + lane) * 8];
      acc[nt] = __builtin_amdgcn_mfma_f32_32x32x16_bf16(ah, bh, acc[nt], 0, 0, 0);
      acc[nt] = __builtin_amdgcn_mfma_f32_32x32x16_bf16(ah, bl, acc[nt], 0, 0, 0);
    }
    if (s + 1 < NODE_CHUNKS) block_sync_lds();
  }

#pragma unroll
  for (int nt = 0; nt < 4; ++nt) {
    float b2 = ub2[nt * 32 + m];
#pragma unroll
    for (int r = 0; r < 16; ++r) {
      int rowi = (r & 3) + 8 * (r >> 2) + 4 * half;
      size_t idx = (size_t)(nb + wid * 32 + rowi) * H + nt * 32 + m;
      float hv = (float)hb[idx];
      hb[idx] = (__bf16)(hv + acc[nt][r] + b2);
    }
  }
}

// ---------------- batch mean pooling (batch is sorted) ----------------
__global__ __launch_bounds__(128) void pool_kernel(
    const __bf16* __restrict__ hb, const int* __restrict__ batch,
    float* __restrict__ pooled, int* __restrict__ counts) {
  int j = threadIdx.x;
  int nbase = blockIdx.x * 128;
  int nend = nbase + 128;
  if (nend > NN) nend = NN;
  if (nbase >= NN) return;
  int cur = batch[nbase];
  float sum = 0.f;
  int cnt = 0;
  for (int n = nbase; n < nend; ++n) {
    int b = batch[n];
    if (b != cur) {
      unsafeAtomicAdd(&pooled[cur * H + j], sum);
      if (j == 0) atomicAdd(&counts[cur], cnt);
      sum = 0.f; cnt = 0; cur = b;
    }
    sum += (float)hb[(size_t)n * H + j];
    cnt++;
  }
  unsafeAtomicAdd(&pooled[cur * H + j], sum);
  if (j == 0) atomicAdd(&counts[cur], cnt);
}

// ---------------- readout MLP: one block per batch ----------------
__global__ __launch_bounds__(128) void readout_kernel(
    const float* __restrict__ pooled, const int* __restrict__ counts,
    const float* __restrict__ gf, const float* __restrict__ Wg,
    const float* __restrict__ bg, const float* __restrict__ rW1,
    const float* __restrict__ rb1, const float* __restrict__ rW2,
    const float* __restrict__ rb2, const float* __restrict__ rW3,
    const float* __restrict__ rb3, float* __restrict__ out) {
  __shared__ float fin[256];
  __shared__ float t1[128];
  __shared__ float t2[64];
  int j = threadIdx.x;
  int b = blockIdx.x;
  float cnt = (float)counts[b];
  if (cnt < 1.f) cnt = 1.f;
  fin[j] = pooled[b * H + j] / cnt;
  fin[H + j] = fmaf(gf[b], Wg[j], bg[j]);
  __syncthreads();
  float a = rb1[j];
  for (int k = 0; k < 256; ++k) a = fmaf(fin[k], rW1[k * H + j], a);
  t1[j] = fmaxf(a, 0.f);
  __syncthreads();
  if (j < 64) {
    float a2 = rb2[j];
    for (int k = 0; k < 128; ++k) a2 = fmaf(t1[k], rW2[k * 64 + j], a2);
    t2[j] = fmaxf(a2, 0.f);
  }
  __syncthreads();
  if (j < 64) {
    float p = t2[j] * rW3[j];
#pragma unroll
    for (int off = 32; off; off >>= 1) p += __shfl_down(p, off);
    if (j == 0) out[b] = p + rb3[0];
  }
}

extern "C" void kernel_launch(void* const* d_in, const int* in_sizes, int n_in,
                              void* d_out, int out_size, void* d_ws, size_t ws_size,
                              hipStream_t stream) {
  const float* x   = (const float*)d_in[0];
  const float* ea  = (const float*)d_in[1];
  const float* gf  = (const float*)d_in[2];
  const int*   ei  = (const int*)d_in[3];
  const int*   bat = (const int*)d_in[4];
  const float* Wn  = (const float*)d_in[5];
  const float* bn  = (const float*)d_in[6];
  const float* We  = (const float*)d_in[7];
  const float* be  = (const float*)d_in[8];
  const float* Wg  = (const float*)d_in[9];
  const float* bg  = (const float*)d_in[10];
  const float* mW1 = (const float*)d_in[11];
  const float* mb1 = (const float*)d_in[12];
  const float* mW2 = (const float*)d_in[13];
  const float* mb2 = (const float*)d_in[14];
  const float* uW1 = (const float*)d_in[15];
  const float* ub1 = (const float*)d_in[16];
  const float* uW2 = (const float*)d_in[17];
  const float* ub2 = (const float*)d_in[18];
  const float* rW1 = (const float*)d_in[19];
  const float* rb1 = (const float*)d_in[20];
  const float* rW2 = (const float*)d_in[21];
  const float* rb2 = (const float*)d_in[22];
  const float* rW3 = (const float*)d_in[23];
  const float* rb3 = (const float*)d_in[24];

  char* p = (char*)d_ws;
  __bf16* hb     = (__bf16*)p; p += (size_t)NPAD * H * 2;        // 12.8 MB
  float*  aggrH  = (float*)p;  p += (size_t)NPAD * H * 4;        // 25.6 MB
  __bf16* z      = (__bf16*)p; p += (size_t)NPAD * 256 * 2;      // 25.6 MB
  __bf16* zePre  = (__bf16*)p; p += (size_t)NE * H * 2;          // 102.4 MB
  __bf16* eaSrt  = (__bf16*)p; p += (size_t)NE * EDIM * 2;       // 12.8 MB
  int*    srcSrt = (int*)p;    p += (size_t)NE * 4;
  int*    eidSrt = (int*)p;    p += (size_t)NE * 4;
  __bf16* ZW     = (__bf16*)p; p += (size_t)NLAYERS * 8 * ZW_CHUNK * 2;
  __bf16* WnS    = (__bf16*)p; p += (size_t)NLAYERS * NODE_CHUNKS * CHUNK_ELEMS * 2;
  __bf16* WefS   = (__bf16*)p; p += (size_t)NLAYERS * CHUNK_ELEMS * 2;
  float*  Wef    = (float*)p;  p += (size_t)NLAYERS * EDIM * H * 4;
  float*  bm     = (float*)p;  p += (size_t)NLAYERS * H * 4;
  float*  Wu     = (float*)p;  p += (size_t)NLAYERS * 256 * H * 4;
  float*  va     = (float*)p;  p += (size_t)NLAYERS * H * 4;
  int*    deg    = (int*)p;    p += (size_t)NPAD * 4;
  int*    cursor = (int*)p;    p += (size_t)NPAD * 4;
  int*    bsum   = (int*)p;    p += 256 * 4;
  int*    boff   = (int*)p;    p += 256 * 4;
  float*  pooled = (float*)p;  p += (size_t)NBATCH * H * 4;
  int*    counts = (int*)p;    p += 64;

  hipMemsetAsync(deg, 0, (size_t)NPAD * 4, stream);
  hipMemsetAsync(cursor, 0, (size_t)NPAD * 4, stream);  // tail stays 0 -> empty segments for pad nodes
  hipMemsetAsync(pooled, 0, (size_t)NBATCH * H * 4, stream);
  hipMemsetAsync(counts, 0, 64, stream);

  embed_nodes_kernel<<<NN / 16, 128, 0, stream>>>(x, Wn, bn, hb);
  degree_kernel<<<(NE + 255) / 256, 256, 0, stream>>>(ei, deg);
  scan1_kernel<<<NSB, 256, 0, stream>>>(deg, bsum);
  scan2_kernel<<<1, 256, 0, stream>>>(bsum, boff);
  scan3_kernel<<<NSB, 256, 0, stream>>>(deg, boff, cursor);
  scatter_kernel<<<(NE + 255) / 256, 256, 0, stream>>>(ei, cursor, srcSrt, eidSrt);
  gather_ea_kernel<<<(NE + 255) / 256, 256, 0, stream>>>(ea, eidSrt, eaSrt);
  precomp_zw_kernel<<<NLAYERS * 8, 256, 0, stream>>>(mW1, ZW);
  precomp_wef_kernel<<<NLAYERS, 128, 0, stream>>>(mW1, mb1, We, be, Wef, bm);
  precomp_wefs_kernel<<<NLAYERS, 256, 0, stream>>>(Wef, WefS);
  precomp_wu_kernel<<<NLAYERS * 257, 128, 0, stream>>>(uW1, mW2, mb2, Wu, va);
  precomp_wns_kernel<<<NLAYERS * NODE_CHUNKS, 256, 0, stream>>>(Wu, uW2, WnS);

  for (int l = 0; l < NLAYERS; ++l) {
    zdzs_kernel<<<NBLK, 256, 0, stream>>>(
        hb, ZW + (size_t)l * 8 * ZW_CHUNK, bm + (size_t)l * H, z);
    ze_kernel<<<NE / ZEB, 256, 0, stream>>>(
        eaSrt, WefS + (size_t)l * CHUNK_ELEMS, zePre);
    edge_aggr_kernel<<<NPAD / 4, 256, 0, stream>>>(
        z, srcSrt, cursor, zePre, aggrH);
    node_update_mfma_kernel<<<NBLK, 256, 0, stream>>>(
        hb, aggrH, deg, WnS + (size_t)l * NODE_CHUNKS * CHUNK_ELEMS,
        ub1 + (size_t)l * H, va + (size_t)l * H, ub2 + (size_t)l * H);
  }

  pool_kernel<<<(NN + 127) / 128, 128, 0, stream>>>(hb, bat, pooled, counts);
  readout_kernel<<<NBATCH, 128, 0, stream>>>(pooled, counts, gf, Wg, bg, rW1,
                                             rb1, rW2, rb2, rW3, rb3,
                                             (float*)d_out);
}